// Round 20
// baseline (105.399 us; speedup 1.0000x reference)
//
#include <hip/hip_runtime.h>

#define T_DIM 512
#define I_DIM 16
#define B_DIM 4096
#define K_CH 16            // steps per chunk (f32 ring = 64 KB, 2 blocks/CU)
#define NCH  (T_DIM / K_CH)
#define COLS 8             // real batch cols per block (16-wide tile, 2x dup)
#define SCL 2.885390081777927f   // 2*log2(e), folded into weights/biases

typedef _Float16 f16x8 __attribute__((ext_vector_type(8)));
typedef float f32x4 __attribute__((ext_vector_type(4)));
typedef __fp16 hf2v __attribute__((ext_vector_type(2)));

union Frag { f16x8 v; __fp16 e[8]; uint4 u; };

// pre-activation already scaled by 2*log2(e): tanh = 1 - 2/(exp2(u)+1)
__device__ __forceinline__ float tanh_s(float u) {
    float e = __builtin_amdgcn_exp2f(u);
    return fmaf(-2.f, __builtin_amdgcn_rcpf(e + 1.f), 1.f);
}

__device__ __forceinline__ f16x8 pack8(float a0, float a1, float a2, float a3,
                                       float b0, float b1, float b2, float b3) {
    Frag f;
    hf2v p0 = __builtin_amdgcn_cvt_pkrtz(a0, a1);
    hf2v p1 = __builtin_amdgcn_cvt_pkrtz(a2, a3);
    hf2v p2 = __builtin_amdgcn_cvt_pkrtz(b0, b1);
    hf2v p3 = __builtin_amdgcn_cvt_pkrtz(b2, b3);
    f.e[0] = p0[0]; f.e[1] = p0[1]; f.e[2] = p1[0]; f.e[3] = p1[1];
    f.e[4] = p2[0]; f.e[5] = p2[1]; f.e[6] = p3[0]; f.e[7] = p3[1];
    return f.v;
}
__device__ __forceinline__ f16x8 tanhpack_s(f32x4 a, f32x4 b) {
    return pack8(tanh_s(a[0]), tanh_s(a[1]), tanh_s(a[2]), tanh_s(a[3]),
                 tanh_s(b[0]), tanh_s(b[1]), tanh_s(b[2]), tanh_s(b[3]));
}
// q-permuted A-frag loads (q(8g+j) = 4g+j | 16+4g+j-4), verified r15-r19,
// tanh scale folded in.
__device__ __forceinline__ f16x8 loadWq32s(const float* W, int row, int g) {
    float4 a = *reinterpret_cast<const float4*>(W + row * 32 + 4 * g);
    float4 b = *reinterpret_cast<const float4*>(W + row * 32 + 16 + 4 * g);
    return pack8(a.x*SCL, a.y*SCL, a.z*SCL, a.w*SCL, b.x*SCL, b.y*SCL, b.z*SCL, b.w*SCL);
}
__device__ __forceinline__ f16x8 loadWq16s(const float* W, int row, int g) {
    float4 a = *reinterpret_cast<const float4*>(W + row * 16 + 4 * g);
    return pack8(a.x*SCL, a.y*SCL, a.z*SCL, a.w*SCL, 0.f, 0.f, 0.f, 0.f);
}

// r19 structure, rebalanced: the PRODUCER also computes pd1 = Wih1*h1 + b1
// (2 MFMAs in its own latency shadow) and the ring carries f32 pd1 instead of
// f16 h1. Consumer: 2 chain MFMAs + 2 ds_read_b128 + 8 tanh per step.
__global__ void __launch_bounds__(128)
rnn2_pd1_kernel(const float* __restrict__ x,
                const float* __restrict__ Wih0, const float* __restrict__ Whh0,
                const float* __restrict__ bih0, const float* __restrict__ bhh0,
                const float* __restrict__ Wih1, const float* __restrict__ Whh1,
                const float* __restrict__ bih1, const float* __restrict__ bhh1,
                const float* __restrict__ fcw, const float* __restrict__ fcb,
                float* __restrict__ out)
{
    const int tid = threadIdx.x;
    const int l   = tid & 63;
    const int wid = tid >> 6;
    const int c   = l & 15;
    const int g   = l >> 4;
    const int rowbase = blockIdx.x * COLS;

    __shared__ float ring[2][K_CH][2][64][4];   // f32 pd1, 64 KB

    f16x8 wHH[2], wIH1[2], wIH0[2];
    f32x4 b0C[2], b1C[2];
    Frag  h1f;
    f32x4 Xacc[2];
    float4 xp0, xp1, xp2, xp3, xp4, xp5, xp6, xp7;
    const float* xlane = nullptr;
    float h20=0.f,h21=0.f,h22=0.f,h23=0.f,h24=0.f,h25=0.f,h26=0.f,h27=0.f;
    Frag h2f; h2f.u = make_uint4(0u, 0u, 0u, 0u);   // h2(-1) = 0

    if (wid == 0) {
#pragma unroll
        for (int tt = 0; tt < 2; ++tt) {
            const int row = c + 16 * tt;
            wHH[tt]  = loadWq32s(Whh0, row, g);
            wIH0[tt] = loadWq16s(Wih0, row, g);
            wIH1[tt] = loadWq32s(Wih1, row, g);
            const int r0 = 4 * g + 16 * tt;
            float4 bi0 = *reinterpret_cast<const float4*>(bih0 + r0);
            float4 bh0 = *reinterpret_cast<const float4*>(bhh0 + r0);
            b0C[tt][0] = (bi0.x + bh0.x) * SCL; b0C[tt][1] = (bi0.y + bh0.y) * SCL;
            b0C[tt][2] = (bi0.z + bh0.z) * SCL; b0C[tt][3] = (bi0.w + bh0.w) * SCL;
            float4 bi1 = *reinterpret_cast<const float4*>(bih1 + r0);
            float4 bh1 = *reinterpret_cast<const float4*>(bhh1 + r0);
            b1C[tt][0] = (bi1.x + bh1.x) * SCL; b1C[tt][1] = (bi1.y + bh1.y) * SCL;
            b1C[tt][2] = (bi1.z + bh1.z) * SCL; b1C[tt][3] = (bi1.w + bh1.w) * SCL;
        }
        const size_t xcol = rowbase + (c & (COLS - 1));
        xlane = x + xcol * (size_t)(T_DIM * I_DIM) + 4 * g;
    } else {
#pragma unroll
        for (int tt = 0; tt < 2; ++tt) {
            wHH[tt] = loadWq32s(Whh1, c + 16 * tt, g);   // consumer: only Whh1
        }
    }

// producer step: D0 chain, pd1 off-chain, f32 ring write, Xacc refresh
#define PSTEP(t, P)                                                                         \
    {                                                                                       \
        f32x4 D0a = __builtin_amdgcn_mfma_f32_16x16x32_f16(wHH[0], h1f.v, Xacc[0], 0,0,0);  \
        f32x4 D0b = __builtin_amdgcn_mfma_f32_16x16x32_f16(wHH[1], h1f.v, Xacc[1], 0,0,0);  \
        Frag xf; xf.v = pack8((P).x, (P).y, (P).z, (P).w, 0.f, 0.f, 0.f, 0.f);              \
        const int tn = ((t) + 9 < T_DIM) ? (t) + 9 : (T_DIM - 1);                           \
        (P) = *reinterpret_cast<const float4*>(xlane + (size_t)tn * I_DIM);                 \
        h1f.v = tanhpack_s(D0a, D0b);                                                       \
        f32x4 pa = __builtin_amdgcn_mfma_f32_16x16x32_f16(wIH1[0], h1f.v, b1C[0], 0,0,0);   \
        f32x4 pb = __builtin_amdgcn_mfma_f32_16x16x32_f16(wIH1[1], h1f.v, b1C[1], 0,0,0);   \
        *reinterpret_cast<f32x4*>(&ring[((t) / K_CH) & 1][(t) & (K_CH - 1)][0][l][0]) = pa; \
        *reinterpret_cast<f32x4*>(&ring[((t) / K_CH) & 1][(t) & (K_CH - 1)][1][l][0]) = pb; \
        Xacc[0] = __builtin_amdgcn_mfma_f32_16x16x32_f16(wIH0[0], xf.v, b0C[0], 0,0,0);     \
        Xacc[1] = __builtin_amdgcn_mfma_f32_16x16x32_f16(wIH0[1], xf.v, b0C[1], 0,0,0);     \
    }

#pragma unroll 1
    for (int p = 0; p <= NCH; ++p) {
        if (wid == 0 && p < NCH) {
            if (p == 0) {
                // ---- serial prologue: h1(0..7) + pd1(0..7) into ring ----
#pragma unroll
                for (int t = 0; t < 8; ++t) {
                    float4 xq = *reinterpret_cast<const float4*>(xlane + (size_t)t * I_DIM);
                    Frag xg; xg.v = pack8(xq.x, xq.y, xq.z, xq.w, 0.f, 0.f, 0.f, 0.f);
                    f32x4 X0 = __builtin_amdgcn_mfma_f32_16x16x32_f16(wIH0[0], xg.v, b0C[0], 0,0,0);
                    f32x4 X1 = __builtin_amdgcn_mfma_f32_16x16x32_f16(wIH0[1], xg.v, b0C[1], 0,0,0);
                    f32x4 D0, D1;
                    if (t == 0) { D0 = X0; D1 = X1; }
                    else {
                        D0 = __builtin_amdgcn_mfma_f32_16x16x32_f16(wHH[0], h1f.v, X0, 0,0,0);
                        D1 = __builtin_amdgcn_mfma_f32_16x16x32_f16(wHH[1], h1f.v, X1, 0,0,0);
                    }
                    h1f.v = tanhpack_s(D0, D1);
                    f32x4 pa = __builtin_amdgcn_mfma_f32_16x16x32_f16(wIH1[0], h1f.v, b1C[0], 0,0,0);
                    f32x4 pb = __builtin_amdgcn_mfma_f32_16x16x32_f16(wIH1[1], h1f.v, b1C[1], 0,0,0);
                    *reinterpret_cast<f32x4*>(&ring[0][t][0][l][0]) = pa;
                    *reinterpret_cast<f32x4*>(&ring[0][t][1][l][0]) = pb;
                }
                // Xacc = fold x(8); fill 8-deep prefetch ring with x(9..16)
                {
                    float4 xq = *reinterpret_cast<const float4*>(xlane + 8 * I_DIM);
                    Frag xg; xg.v = pack8(xq.x, xq.y, xq.z, xq.w, 0.f, 0.f, 0.f, 0.f);
                    Xacc[0] = __builtin_amdgcn_mfma_f32_16x16x32_f16(wIH0[0], xg.v, b0C[0], 0,0,0);
                    Xacc[1] = __builtin_amdgcn_mfma_f32_16x16x32_f16(wIH0[1], xg.v, b0C[1], 0,0,0);
                }
                xp0 = *reinterpret_cast<const float4*>(xlane +  9 * I_DIM);
                xp1 = *reinterpret_cast<const float4*>(xlane + 10 * I_DIM);
                xp2 = *reinterpret_cast<const float4*>(xlane + 11 * I_DIM);
                xp3 = *reinterpret_cast<const float4*>(xlane + 12 * I_DIM);
                xp4 = *reinterpret_cast<const float4*>(xlane + 13 * I_DIM);
                xp5 = *reinterpret_cast<const float4*>(xlane + 14 * I_DIM);
                xp6 = *reinterpret_cast<const float4*>(xlane + 15 * I_DIM);
                xp7 = *reinterpret_cast<const float4*>(xlane + 16 * I_DIM);
                // steps 8..15 complete chunk 0
                PSTEP( 8, xp0) PSTEP( 9, xp1) PSTEP(10, xp2) PSTEP(11, xp3)
                PSTEP(12, xp4) PSTEP(13, xp5) PSTEP(14, xp6) PSTEP(15, xp7)
            } else {
                const int t0 = p * K_CH;
                PSTEP(t0 +  0, xp0) PSTEP(t0 +  1, xp1)
                PSTEP(t0 +  2, xp2) PSTEP(t0 +  3, xp3)
                PSTEP(t0 +  4, xp4) PSTEP(t0 +  5, xp5)
                PSTEP(t0 +  6, xp6) PSTEP(t0 +  7, xp7)
                PSTEP(t0 +  8, xp0) PSTEP(t0 +  9, xp1)
                PSTEP(t0 + 10, xp2) PSTEP(t0 + 11, xp3)
                PSTEP(t0 + 12, xp4) PSTEP(t0 + 13, xp5)
                PSTEP(t0 + 14, xp6) PSTEP(t0 + 15, xp7)
            }
        }
        if (wid == 1 && p >= 1) {
            const int buf = (p - 1) & 1;
            f32x4 lda = *reinterpret_cast<const f32x4*>(&ring[buf][0][0][l][0]);
            f32x4 ldb = *reinterpret_cast<const f32x4*>(&ring[buf][0][1][l][0]);
#pragma unroll 2
            for (int s = 0; s < K_CH; ++s) {
                f32x4 D1a = __builtin_amdgcn_mfma_f32_16x16x32_f16(wHH[0], h2f.v, lda, 0,0,0);
                f32x4 D1b = __builtin_amdgcn_mfma_f32_16x16x32_f16(wHH[1], h2f.v, ldb, 0,0,0);
                const int sn = (s + 1 < K_CH) ? s + 1 : s;
                lda = *reinterpret_cast<const f32x4*>(&ring[buf][sn][0][l][0]);
                ldb = *reinterpret_cast<const f32x4*>(&ring[buf][sn][1][l][0]);
                h20 = tanh_s(D1a[0]); h21 = tanh_s(D1a[1]);
                h22 = tanh_s(D1a[2]); h23 = tanh_s(D1a[3]);
                h24 = tanh_s(D1b[0]); h25 = tanh_s(D1b[1]);
                h26 = tanh_s(D1b[2]); h27 = tanh_s(D1b[3]);
                h2f.v = pack8(h20, h21, h22, h23, h24, h25, h26, h27);
            }
        }
        __syncthreads();
    }
#undef PSTEP

    // ---- FC epilogue from the consumer's h2(T-1) registers ----
    if (wid == 1) {
        float4 fw0 = *reinterpret_cast<const float4*>(fcw + 4 * g);
        float4 fw1 = *reinterpret_cast<const float4*>(fcw + 16 + 4 * g);
        float part = fw0.x * h20 + fw0.y * h21 + fw0.z * h22 + fw0.w * h23
                   + fw1.x * h24 + fw1.y * h25 + fw1.z * h26 + fw1.w * h27;
        part += __shfl_xor(part, 16, 64);
        part += __shfl_xor(part, 32, 64);
        if (l < COLS) out[rowbase + l] = part + fcb[0];
    }
}

extern "C" void kernel_launch(void* const* d_in, const int* in_sizes, int n_in,
                              void* d_out, int out_size, void* d_ws, size_t ws_size,
                              hipStream_t stream) {
    const float* x    = (const float*)d_in[0];
    const float* Wih0 = (const float*)d_in[1];
    const float* Whh0 = (const float*)d_in[2];
    const float* bih0 = (const float*)d_in[3];
    const float* bhh0 = (const float*)d_in[4];
    const float* Wih1 = (const float*)d_in[5];
    const float* Whh1 = (const float*)d_in[6];
    const float* bih1 = (const float*)d_in[7];
    const float* bhh1 = (const float*)d_in[8];
    const float* fcw  = (const float*)d_in[9];
    const float* fcb  = (const float*)d_in[10];
    float* out = (float*)d_out;

    dim3 grid(B_DIM / COLS);   // 512 blocks x 2 waves = 1024 waves
    rnn2_pd1_kernel<<<grid, 128, 0, stream>>>(x, Wih0, Whh0, bih0, bhh0,
                                              Wih1, Whh1, bih1, bhh1,
                                              fcw, fcb, out);
}